// Round 6
// baseline (945.246 us; speedup 1.0000x reference)
//
#include <hip/hip_runtime.h>
#include <hip/hip_bf16.h>

typedef __bf16 bf16_t;
typedef __bf16 bf16x8 __attribute__((ext_vector_type(8)));
typedef float  f32x4  __attribute__((ext_vector_type(4)));

static __device__ __forceinline__ f32x4 mfma16(bf16x8 a, bf16x8 b, f32x4 c) {
    return __builtin_amdgcn_mfma_f32_16x16x32_bf16(a, b, c, 0, 0, 0);
}

// ---------------------------------------------------------------------------
// h_phys permutation: sig(ht, p) = 32*(ht>>1) + 8*(p>>2) + 4*(ht&1) + (p&3).
// With this ordering, the L1 MFMA output registers at lane (g,c) are exactly
// the L2 A/B-fragment elements k_phys = 32*ks + 8*g + j for ks = ht>>1 —
// a1 never leaves registers (no LDS, no shuffles, no barriers).
//
// W1ef[(ht*64 + l)*8 + j]         = W1[128 + 8g + j][sig(ht, c)]
// W2f [((ks*16+ct)*64 + l)*8 + j] = W2[32ks + 8g + 4*(j>>2) + (j&3)][ct*16+c]
// ---------------------------------------------------------------------------
__global__ void prep_pack(const float* __restrict__ W1, const float* __restrict__ W2,
                          bf16_t* __restrict__ W1ef, bf16_t* __restrict__ W2f) {
    int t = blockIdx.x * blockDim.x + threadIdx.x;
    int l = t & 63, g = l >> 4, c = l & 15;
    if (t < 1024) {                       // W1 edge rows, sigma-permuted cols
        int ht = t >> 6;
        int hcol = 32 * (ht >> 1) + 8 * (c >> 2) + 4 * (ht & 1) + (c & 3);
        #pragma unroll
        for (int j = 0; j < 8; ++j)
            W1ef[t * 8 + j] = (bf16_t)W1[(128 + 8 * g + j) * 256 + hcol];
    } else if (t < 1024 + 8192) {         // W2, sigma-permuted k rows
        int t2 = t - 1024;
        int ks = t2 >> 10;
        int ct = (t2 >> 6) & 15;
        #pragma unroll
        for (int j = 0; j < 8; ++j) {
            int krow = 32 * ks + 8 * g + 4 * (j >> 2) + (j & 3);
            W2f[t2 * 8 + j] = (bf16_t)W2[krow * 256 + ct * 16 + c];
        }
    }
}

// ---------------------------------------------------------------------------
// Pi[b,i,h] = nodes[b,i,:] @ W1[0:128,h] + b1[h]   (f32, logical h order)
// Pj[b,j,h] = nodes[b,j,:] @ W1[160:288,h]         (f32, logical h order)
// ---------------------------------------------------------------------------
__global__ __launch_bounds__(256) void prep_pij(const float* __restrict__ nodes,
                                                const float* __restrict__ W1,
                                                const float* __restrict__ b1,
                                                float* __restrict__ Pi,
                                                float* __restrict__ Pj) {
    int b = blockIdx.x >> 2;
    int q = blockIdx.x & 3;
    int h = threadIdx.x;
    const float* nb = nodes + (b * 64 + q * 16) * 128;
    float ai[16], aj[16];
    float bias = b1[h];
    #pragma unroll
    for (int ii = 0; ii < 16; ++ii) { ai[ii] = bias; aj[ii] = 0.f; }
    for (int d = 0; d < 128; ++d) {
        float wi = W1[d * 256 + h];
        float wj = W1[(160 + d) * 256 + h];
        #pragma unroll
        for (int ii = 0; ii < 16; ++ii) {
            float s = nb[ii * 128 + d];
            ai[ii] = fmaf(s, wi, ai[ii]);
            aj[ii] = fmaf(s, wj, aj[ii]);
        }
    }
    #pragma unroll
    for (int ii = 0; ii < 16; ++ii) {
        Pi[(b * 64 + q * 16 + ii) * 256 + h] = ai[ii];
        Pj[(b * 64 + q * 16 + ii) * 256 + h] = aj[ii];
    }
}

// ---------------------------------------------------------------------------
// Barrier-free fused MLP. 256 blocks (1/CU) x 512 thr (8 waves, 2/SIMD).
// W2f staged to LDS once; then each wave independently processes 8 iters of
// 32 pairs: L1 MFMA -> (+Pi+Pj, relu, cvt) -> a1 stays in registers as L2
// B-fragments (sigma trick) -> L2 MFMA (W2 frags from LDS) -> in-lane L3.
// No __syncthreads after staging; no inter-wave data sharing at all.
// ---------------------------------------------------------------------------
__global__ __launch_bounds__(512, 2) void mlp_main(
    const float* __restrict__ edges,
    const float* __restrict__ Pi, const float* __restrict__ Pj,
    const bf16_t* __restrict__ W1ef, const bf16_t* __restrict__ W2f,
    const float* __restrict__ b2, const float* __restrict__ W3,
    const float* __restrict__ b3, float* __restrict__ out) {

    __shared__ bf16_t w2lds[65536];       // 128 KB: full W2 fragment bank

    const int p = blockIdx.x;
    const int xb = (p & 7) * 32 + (p >> 3);    // 256 = 8 XCD x 32 CU
    const int tid = threadIdx.x;
    const int w = tid >> 6, l = tid & 63, g = l >> 4, c = l & 15;

    // stage W2f -> LDS (one time), coalesced 16B per thread per step
    #pragma unroll
    for (int k = 0; k < 16; ++k) {
        int idx = k * 512 + tid;
        *(f32x4*)&w2lds[idx * 8] = *(const f32x4*)&W2f[idx * 8];
    }
    __syncthreads();                      // the only barrier in this kernel

    const float bias3 = b3[0];
    const long blockbase = (long)xb * 2048;    // 2048 pairs per block
    const int b = xb >> 1;
    const f32x4 z4 = {0.f, 0.f, 0.f, 0.f};

    // prefetch iter 0 edges: pair = blockbase + idx*32 + 16pt + c, idx = t*8+w
    f32x4 e[2][2];
    {
        const float* ep = edges + (blockbase + (long)w * 32 + c) * 32 + 8 * g;
        #pragma unroll
        for (int pt = 0; pt < 2; ++pt) {
            e[pt][0] = *(const f32x4*)(ep + pt * 512);
            e[pt][1] = *(const f32x4*)(ep + pt * 512 + 4);
        }
    }

    for (int t = 0; t < 8; ++t) {
        const int idx = t * 8 + w;
        const long pbase = blockbase + (long)idx * 32;

        // convert current edges to bf16 B-fragments
        bf16x8 ebf[2];
        #pragma unroll
        for (int pt = 0; pt < 2; ++pt)
            #pragma unroll
            for (int j2 = 0; j2 < 4; ++j2) {
                ebf[pt][j2]     = (bf16_t)e[pt][0][j2];
                ebf[pt][4 + j2] = (bf16_t)e[pt][1][j2];
            }

        // prefetch next iter's edges (lands during L1+L2 compute)
        if (t < 7) {
            const float* ep = edges + (pbase + 8 * 32 + c) * 32 + 8 * g;
            #pragma unroll
            for (int pt = 0; pt < 2; ++pt) {
                e[pt][0] = *(const f32x4*)(ep + pt * 512);
                e[pt][1] = *(const f32x4*)(ep + pt * 512 + 4);
            }
        }

        // ---- layer 1 + epilogue, fused per h-tile; a1 -> registers ----
        const float* PiR = Pi + (pbase >> 6) * 256;               // row i, uniform
        const float* PjR = Pj + ((long)b * 64 + (idx & 1) * 32) * 256;
        bf16x8 a1w[2][8];                 // L2 B-fragments, built in place
        #pragma unroll
        for (int ht = 0; ht < 16; ++ht) {
            bf16x8 wfr = *(const bf16x8*)&W1ef[(ht * 64 + l) * 8];
            f32x4 acc0 = mfma16(wfr, ebf[0], z4);
            f32x4 acc1 = mfma16(wfr, ebf[1], z4);
            const int hb = 32 * (ht >> 1) + 8 * g + 4 * (ht & 1); // sigma offset
            f32x4 piv = *(const f32x4*)&PiR[hb];
            f32x4 pj0 = *(const f32x4*)&PjR[(long)c * 256 + hb];
            f32x4 pj1 = *(const f32x4*)&PjR[(long)(16 + c) * 256 + hb];
            #pragma unroll
            for (int r = 0; r < 4; ++r) {
                float v0 = acc0[r] + piv[r] + pj0[r];
                float v1 = acc1[r] + piv[r] + pj1[r];
                v0 = v0 > 0.f ? v0 : 0.f;
                v1 = v1 > 0.f ? v1 : 0.f;
                a1w[0][ht >> 1][4 * (ht & 1) + r] = (bf16_t)v0;
                a1w[1][ht >> 1][4 * (ht & 1) + r] = (bf16_t)v1;
            }
        }

        // ---- layer 2: A = W2 frags (LDS), B = a1 frags (registers) ----
        f32x4 acc2[2][16];
        #pragma unroll
        for (int ks = 0; ks < 8; ++ks) {
            #pragma unroll
            for (int ct = 0; ct < 16; ++ct) {
                bf16x8 w2 = *(const bf16x8*)&w2lds[((ks * 16 + ct) * 64 + l) * 8];
                if (ks == 0) {
                    acc2[0][ct] = mfma16(w2, a1w[0][0], z4);
                    acc2[1][ct] = mfma16(w2, a1w[1][0], z4);
                } else {
                    acc2[0][ct] = mfma16(w2, a1w[0][ks], acc2[0][ct]);
                    acc2[1][ct] = mfma16(w2, a1w[1][ks], acc2[1][ct]);
                }
            }
        }

        // ---- layer 3: relu(a2+b2).W3, in-lane over (ct,r), shfl over g ----
        #pragma unroll
        for (int pt = 0; pt < 2; ++pt) {
            float s = 0.f;
            #pragma unroll
            for (int ct = 0; ct < 16; ++ct) {
                f32x4 b2q = *(const f32x4*)&b2[ct * 16 + 4 * g];
                f32x4 w3q = *(const f32x4*)&W3[ct * 16 + 4 * g];
                #pragma unroll
                for (int r = 0; r < 4; ++r) {
                    float v = acc2[pt][ct][r] + b2q[r];
                    v = v > 0.f ? v : 0.f;
                    s = fmaf(v, w3q[r], s);
                }
            }
            s += __shfl_xor(s, 16);       // sum over the 4 g-groups
            s += __shfl_xor(s, 32);
            if (g == 0) out[pbase + 16 * pt + c] = s + bias3;
        }
    }
}

extern "C" void kernel_launch(void* const* d_in, const int* in_sizes, int n_in,
                              void* d_out, int out_size, void* d_ws, size_t ws_size,
                              hipStream_t stream) {
    const float* nodes = (const float*)d_in[0];
    const float* edges = (const float*)d_in[1];
    const float* W1    = (const float*)d_in[2];
    const float* b1    = (const float*)d_in[3];
    const float* W2    = (const float*)d_in[4];
    const float* b2    = (const float*)d_in[5];
    const float* W3    = (const float*)d_in[6];
    const float* b3    = (const float*)d_in[7];
    float* out = (float*)d_out;

    char* ws = (char*)d_ws;
    float*  Pi   = (float*)ws;                                        // 8 MB
    float*  Pj   = (float*)(ws + (size_t)8 * 1024 * 1024);            // 8 MB
    bf16_t* W2f  = (bf16_t*)(ws + (size_t)16 * 1024 * 1024);          // 128 KB
    bf16_t* W1ef = (bf16_t*)(ws + (size_t)16 * 1024 * 1024 + 131072); // 16 KB

    prep_pack<<<dim3(36), dim3(256), 0, stream>>>(W1, W2, W1ef, W2f);
    prep_pij<<<dim3(512), dim3(256), 0, stream>>>(nodes, W1, b1, Pi, Pj);
    mlp_main<<<dim3(256), dim3(512), 0, stream>>>(edges, Pi, Pj, W1ef, W2f, b2, W3, b3, out);
}

// Round 7
// 258.322 us; speedup vs baseline: 3.6592x; 3.6592x over previous
//
#include <hip/hip_runtime.h>
#include <hip/hip_bf16.h>

typedef __bf16 bf16_t;
typedef __bf16 bf16x8 __attribute__((ext_vector_type(8)));
typedef float  f32x4  __attribute__((ext_vector_type(4)));

static __device__ __forceinline__ f32x4 mfma16(bf16x8 a, bf16x8 b, f32x4 c) {
    return __builtin_amdgcn_mfma_f32_16x16x32_bf16(a, b, c, 0, 0, 0);
}

// ---------------------------------------------------------------------------
// sigma packs (R6-verified on HW):
// h_phys(ht,p) = 32*(ht>>1) + 8*(p>>2) + 4*(ht&1) + (p&3): L1 MFMA output at
// lane (g,c), ht-pair (2z,2z+1) forms the k-octet [32*ks+8g .. +7] (ks=ht>>1)
// of the L2 A-fragment at the SAME lane -> a1 goes reg -> one ds_write_b128.
// W1ef[(ht*64+l)*8+j]          = W1[128+8g+j][sig(ht,c)]
// W2f [((ks*16+ct)*64+l)*8+j]  = W2[32ks+8g+4*(j>>2)+(j&3)][ct*16+c]
// ---------------------------------------------------------------------------
__global__ void prep_pack(const float* __restrict__ W1, const float* __restrict__ W2,
                          bf16_t* __restrict__ W1ef, bf16_t* __restrict__ W2f) {
    int t = blockIdx.x * blockDim.x + threadIdx.x;
    int l = t & 63, g = l >> 4, c = l & 15;
    if (t < 1024) {
        int ht = t >> 6;
        int hcol = 32 * (ht >> 1) + 8 * (c >> 2) + 4 * (ht & 1) + (c & 3);
        #pragma unroll
        for (int j = 0; j < 8; ++j)
            W1ef[t * 8 + j] = (bf16_t)W1[(128 + 8 * g + j) * 256 + hcol];
    } else if (t < 1024 + 8192) {
        int t2 = t - 1024;
        int ks = t2 >> 10;
        int ct = (t2 >> 6) & 15;
        #pragma unroll
        for (int j = 0; j < 8; ++j) {
            int krow = 32 * ks + 8 * g + 4 * (j >> 2) + (j & 3);
            W2f[t2 * 8 + j] = (bf16_t)W2[krow * 256 + ct * 16 + c];
        }
    }
}

// ---------------------------------------------------------------------------
// Pi[b,i,h] = nodes[b,i,:] @ W1[0:128,h] + b1[h]   (f32)
// Pjb[b,j,h] = bf16( nodes[b,j,:] @ W1[160:288,h] )
// ---------------------------------------------------------------------------
__global__ __launch_bounds__(256) void prep_pij(const float* __restrict__ nodes,
                                                const float* __restrict__ W1,
                                                const float* __restrict__ b1,
                                                float* __restrict__ Pi,
                                                bf16_t* __restrict__ Pjb) {
    int b = blockIdx.x >> 2;
    int q = blockIdx.x & 3;
    int h = threadIdx.x;
    const float* nb = nodes + (b * 64 + q * 16) * 128;
    float ai[16], aj[16];
    float bias = b1[h];
    #pragma unroll
    for (int ii = 0; ii < 16; ++ii) { ai[ii] = bias; aj[ii] = 0.f; }
    for (int d = 0; d < 128; ++d) {
        float wi = W1[d * 256 + h];
        float wj = W1[(160 + d) * 256 + h];
        #pragma unroll
        for (int ii = 0; ii < 16; ++ii) {
            float s = nb[ii * 128 + d];
            ai[ii] = fmaf(s, wi, ai[ii]);
            aj[ii] = fmaf(s, wj, aj[ii]);
        }
    }
    #pragma unroll
    for (int ii = 0; ii < 16; ++ii) {
        Pi[(b * 64 + q * 16 + ii) * 256 + h] = ai[ii];
        Pjb[(b * 64 + q * 16 + ii) * 256 + h] = (bf16_t)aj[ii];
    }
}

// ---------------------------------------------------------------------------
// v7: 512 blocks (2/CU by LDS+VGPR) x 512 thr, 16 batches of 64 pairs (one
// source node i each). One barrier per batch (all buffers double-buffered).
// L1 (sigma): wave w computes h-octet ks=w for all 4 pair-tiles, writes a1f
//   fragment-linear (1 ds_write_b128 per pt, lane-linear, conflict-free).
// L2: wave w owns out-cols [32w,32w+32): 8 ks x (4 af ds_read_b128 + 2 W2f
//   16B L2$ loads + 8 MFMA), acc2[4][2]=32 regs. In-lane L3 + 2 shfl.
// Cross-wave h-sum via part[] (dbuf), out deferred one batch.
// ---------------------------------------------------------------------------
__global__ __launch_bounds__(512, 4) void mlp_main(
    const float* __restrict__ edges,
    const float* __restrict__ Pi, const bf16_t* __restrict__ Pjb,
    const bf16_t* __restrict__ W1ef, const bf16_t* __restrict__ W2f,
    const float* __restrict__ b2, const float* __restrict__ W3,
    const float* __restrict__ b3, float* __restrict__ out) {

    __shared__ bf16_t a1f[2][16384];      // 2 x 32 KB fragment-linear a1
    __shared__ bf16_t elds[2][2048];      // 2 x 4 KB edge fragments (bf16)
    __shared__ float part[2][8][64];      // 2 x 2 KB partial h-sums

    const int p = blockIdx.x;
    const int xb = (p & 7) * 64 + (p >> 3);    // XCD swizzle (512 % 8 == 0)
    const int tid = threadIdx.x;
    const int w = tid >> 6, l = tid & 63, g = l >> 4, c = l & 15;
    const int b = xb >> 2;
    const f32x4 z4 = {0.f, 0.f, 0.f, 0.f};

    // ---- hoisted invariants (small!) ----
    bf16x8 wf[2];                          // W1e frags, ht = 2w, 2w+1
    #pragma unroll
    for (int z = 0; z < 2; ++z)
        wf[z] = *(const bf16x8*)&W1ef[((2 * w + z) * 64 + l) * 8];

    bf16x8 pjb[4];                         // Pj octets: block-invariant (b fixed)
    #pragma unroll
    for (int pt = 0; pt < 4; ++pt)
        pjb[pt] = *(const bf16x8*)&Pjb[((long)(b * 64 + 16 * pt + c)) * 256
                                       + 32 * w + 8 * g];

    const float bias3 = b3[0];

    // stage mapping: tid<256 stages unit u=tid: (spt, sg, sc)
    const int spt = tid >> 6, sg = (tid >> 4) & 3, sc = tid & 15;
    const long erowbase = (long)xb * 1024 + 16 * spt + sc;

    f32x4 es0, es1;                        // in-flight staged edges
    if (tid < 256) {
        const float* ep = edges + erowbase * 32 + 8 * sg;
        es0 = *(const f32x4*)ep; es1 = *(const f32x4*)(ep + 4);
    }
    const float* PiB = Pi + ((long)xb * 16) * 256 + 32 * w + 8 * g;
    f32x4 pva0 = *(const f32x4*)PiB;       // Pi octet for batch 0
    f32x4 pva1 = *(const f32x4*)(PiB + 4);

    if (tid < 256) {                       // write batch-0 edges
        bf16x8 ev;
        #pragma unroll
        for (int j = 0; j < 4; ++j) { ev[j] = (bf16_t)es0[j]; ev[4 + j] = (bf16_t)es1[j]; }
        *(bf16x8*)&elds[0][tid * 8] = ev;
    }
    __syncthreads();

    f32x4 pvb0, pvb1;

    for (int t = 0; t < 16; ++t) {
        const int cur = t & 1;

        // issue next batch's loads early (hidden under L1+L2 of this batch)
        if (t < 15) {
            if (tid < 256) {
                const float* ep = edges + (erowbase + 64 * (t + 1)) * 32 + 8 * sg;
                es0 = *(const f32x4*)ep; es1 = *(const f32x4*)(ep + 4);
            }
            const float* pp = PiB + (t + 1) * 256;
            pvb0 = *(const f32x4*)pp; pvb1 = *(const f32x4*)(pp + 4);
        }

        // ---------------- layer 1 (sigma-fused, reg -> LDS octets) ----------
        {
            bf16x8 ebf[4];
            #pragma unroll
            for (int pt = 0; pt < 4; ++pt)
                ebf[pt] = *(const bf16x8*)&elds[cur][(pt * 64 + l) * 8];
            #pragma unroll
            for (int pt = 0; pt < 4; ++pt) {
                bf16x8 o;
                #pragma unroll
                for (int z = 0; z < 2; ++z) {
                    f32x4 a = mfma16(wf[z], ebf[pt], z4);
                    f32x4 pv = z ? pva1 : pva0;
                    #pragma unroll
                    for (int r = 0; r < 4; ++r) {
                        float v = a[r] + pv[r] + (float)pjb[pt][4 * z + r];
                        v = v > 0.f ? v : 0.f;
                        o[4 * z + r] = (bf16_t)v;
                    }
                }
                *(bf16x8*)&a1f[cur][((pt * 8 + w) * 64 + l) * 8] = o;
            }
        }

        // write-late: staged edges for batch t+1 into the other elds buffer
        if (t < 15 && tid < 256) {
            bf16x8 ev;
            #pragma unroll
            for (int j = 0; j < 4; ++j) { ev[j] = (bf16_t)es0[j]; ev[4 + j] = (bf16_t)es1[j]; }
            *(bf16x8*)&elds[cur ^ 1][tid * 8] = ev;
        }
        __syncthreads();                   // the one barrier per batch

        // deferred out-write for batch t-1 (all waves' part complete)
        if (t > 0 && tid < 64) {
            float s = bias3;
            #pragma unroll
            for (int ww = 0; ww < 8; ++ww) s += part[cur ^ 1][ww][tid];
            out[(long)xb * 1024 + (t - 1) * 64 + tid] = s;
        }

        // ---------------- layer 2 + layer 3 ----------------
        {
            f32x4 acc2[4][2];
            #pragma unroll
            for (int pt = 0; pt < 4; ++pt) { acc2[pt][0] = z4; acc2[pt][1] = z4; }
            #pragma unroll
            for (int ks = 0; ks < 8; ++ks) {
                bf16x8 af[4];
                #pragma unroll
                for (int pt = 0; pt < 4; ++pt)
                    af[pt] = *(const bf16x8*)&a1f[cur][((pt * 8 + ks) * 64 + l) * 8];
                #pragma unroll
                for (int cc = 0; cc < 2; ++cc) {
                    bf16x8 w2 = *(const bf16x8*)&W2f[((ks * 16 + 2 * w + cc) * 64 + l) * 8];
                    #pragma unroll
                    for (int pt = 0; pt < 4; ++pt)
                        acc2[pt][cc] = mfma16(w2, af[pt], acc2[pt][cc]);
                }
            }
            // L3: col = 32w + 16cc + 4g + r (in-lane), pair = 16pt + c
            f32x4 b2q[2], w3q[2];
            #pragma unroll
            for (int cc = 0; cc < 2; ++cc) {
                b2q[cc] = *(const f32x4*)&b2[32 * w + 16 * cc + 4 * g];
                w3q[cc] = *(const f32x4*)&W3[32 * w + 16 * cc + 4 * g];
            }
            #pragma unroll
            for (int pt = 0; pt < 4; ++pt) {
                float s = 0.f;
                #pragma unroll
                for (int cc = 0; cc < 2; ++cc)
                    #pragma unroll
                    for (int r = 0; r < 4; ++r) {
                        float v = acc2[pt][cc][r] + b2q[cc][r];
                        v = v > 0.f ? v : 0.f;
                        s = fmaf(v, w3q[cc][r], s);
                    }
                s += __shfl_xor(s, 16);    // sum the 4 g-groups
                s += __shfl_xor(s, 32);
                if (g == 0) part[cur][w][pt * 16 + c] = s;
            }
        }
        pva0 = pvb0; pva1 = pvb1;
    }

    __syncthreads();
    if (tid < 64) {                        // out for batch 15
        float s = bias3;
        #pragma unroll
        for (int ww = 0; ww < 8; ++ww) s += part[1][ww][tid];
        out[(long)xb * 1024 + 15 * 64 + tid] = s;
    }
}

extern "C" void kernel_launch(void* const* d_in, const int* in_sizes, int n_in,
                              void* d_out, int out_size, void* d_ws, size_t ws_size,
                              hipStream_t stream) {
    const float* nodes = (const float*)d_in[0];
    const float* edges = (const float*)d_in[1];
    const float* W1    = (const float*)d_in[2];
    const float* b1    = (const float*)d_in[3];
    const float* W2    = (const float*)d_in[4];
    const float* b2    = (const float*)d_in[5];
    const float* W3    = (const float*)d_in[6];
    const float* b3    = (const float*)d_in[7];
    float* out = (float*)d_out;

    char* ws = (char*)d_ws;
    float*  Pi   = (float*)ws;                                        // 8 MB
    bf16_t* Pjb  = (bf16_t*)(ws + (size_t)8 * 1024 * 1024);           // 4 MB
    bf16_t* W2f  = (bf16_t*)(ws + (size_t)12 * 1024 * 1024);          // 128 KB
    bf16_t* W1ef = (bf16_t*)(ws + (size_t)12 * 1024 * 1024 + 131072); // 16 KB

    prep_pack<<<dim3(36), dim3(256), 0, stream>>>(W1, W2, W1ef, W2f);
    prep_pij<<<dim3(512), dim3(256), 0, stream>>>(nodes, W1, b1, Pi, Pjb);
    mlp_main<<<dim3(512), dim3(512), 0, stream>>>(edges, Pi, Pjb, W1ef, W2f, b2, W3, b3, out);
}

// Round 8
// 111.029 us; speedup vs baseline: 8.5135x; 2.3266x over previous
//
#include <hip/hip_runtime.h>
#include <hip/hip_bf16.h>

typedef __bf16 bf16_t;
typedef __bf16 bf16x8 __attribute__((ext_vector_type(8)));
typedef float  f32x4  __attribute__((ext_vector_type(4)));

static __device__ __forceinline__ f32x4 mfma16(bf16x8 a, bf16x8 b, f32x4 c) {
    return __builtin_amdgcn_mfma_f32_16x16x32_bf16(a, b, c, 0, 0, 0);
}

// ---------------------------------------------------------------------------
// sigma packs (R6/R7-verified on HW):
// h_phys(ht,p) = 32*(ht>>1) + 8*(p>>2) + 4*(ht&1) + (p&3): L1 MFMA output at
// lane (g,c), ht-pair (2z,2z+1) forms the k-octet [32*ks+8g .. +7] (ks=ht>>1)
// of the L2 A-fragment at the SAME lane -> a1 goes reg -> one ds_write_b128.
// W1ef[(ht*64+l)*8+j]          = W1[128+8g+j][sig(ht,c)]
// W2f [((ks*16+ct)*64+l)*8+j]  = W2[32ks+8g+4*(j>>2)+(j&3)][ct*16+c]
// ---------------------------------------------------------------------------
__global__ void prep_pack(const float* __restrict__ W1, const float* __restrict__ W2,
                          bf16_t* __restrict__ W1ef, bf16_t* __restrict__ W2f) {
    int t = blockIdx.x * blockDim.x + threadIdx.x;
    int l = t & 63, g = l >> 4, c = l & 15;
    if (t < 1024) {
        int ht = t >> 6;
        int hcol = 32 * (ht >> 1) + 8 * (c >> 2) + 4 * (ht & 1) + (c & 3);
        #pragma unroll
        for (int j = 0; j < 8; ++j)
            W1ef[t * 8 + j] = (bf16_t)W1[(128 + 8 * g + j) * 256 + hcol];
    } else if (t < 1024 + 8192) {
        int t2 = t - 1024;
        int ks = t2 >> 10;
        int ct = (t2 >> 6) & 15;
        #pragma unroll
        for (int j = 0; j < 8; ++j) {
            int krow = 32 * ks + 8 * g + 4 * (j >> 2) + (j & 3);
            W2f[t2 * 8 + j] = (bf16_t)W2[krow * 256 + ct * 16 + c];
        }
    }
}

// ---------------------------------------------------------------------------
// Pi[b,i,h] = nodes[b,i,:] @ W1[0:128,h] + b1[h]   (f32)
// Pjb[b,j,h] = bf16( nodes[b,j,:] @ W1[160:288,h] )
// ---------------------------------------------------------------------------
__global__ __launch_bounds__(256) void prep_pij(const float* __restrict__ nodes,
                                                const float* __restrict__ W1,
                                                const float* __restrict__ b1,
                                                float* __restrict__ Pi,
                                                bf16_t* __restrict__ Pjb) {
    int b = blockIdx.x >> 2;
    int q = blockIdx.x & 3;
    int h = threadIdx.x;
    const float* nb = nodes + (b * 64 + q * 16) * 128;
    float ai[16], aj[16];
    float bias = b1[h];
    #pragma unroll
    for (int ii = 0; ii < 16; ++ii) { ai[ii] = bias; aj[ii] = 0.f; }
    for (int d = 0; d < 128; ++d) {
        float wi = W1[d * 256 + h];
        float wj = W1[(160 + d) * 256 + h];
        #pragma unroll
        for (int ii = 0; ii < 16; ++ii) {
            float s = nb[ii * 128 + d];
            ai[ii] = fmaf(s, wi, ai[ii]);
            aj[ii] = fmaf(s, wj, aj[ii]);
        }
    }
    #pragma unroll
    for (int ii = 0; ii < 16; ++ii) {
        Pi[(b * 64 + q * 16 + ii) * 256 + h] = ai[ii];
        Pjb[(b * 64 + q * 16 + ii) * 256 + h] = (bf16_t)aj[ii];
    }
}

// ---------------------------------------------------------------------------
// v8 == v7 with the ONE fix: __launch_bounds__(512, 2) -> 128-VGPR cap, no
// spill (R7's only defect). 512 blocks (2/CU by LDS) x 512 thr, 16 batches
// of 64 pairs. One barrier per batch.
// ---------------------------------------------------------------------------
__global__ __launch_bounds__(512, 2) void mlp_main(
    const float* __restrict__ edges,
    const float* __restrict__ Pi, const bf16_t* __restrict__ Pjb,
    const bf16_t* __restrict__ W1ef, const bf16_t* __restrict__ W2f,
    const float* __restrict__ b2, const float* __restrict__ W3,
    const float* __restrict__ b3, float* __restrict__ out) {

    __shared__ bf16_t a1f[2][16384];      // 2 x 32 KB fragment-linear a1
    __shared__ bf16_t elds[2][2048];      // 2 x 4 KB edge fragments (bf16)
    __shared__ float part[2][8][64];      // 2 x 2 KB partial h-sums

    const int p = blockIdx.x;
    const int xb = (p & 7) * 64 + (p >> 3);    // XCD swizzle (512 % 8 == 0)
    const int tid = threadIdx.x;
    const int w = tid >> 6, l = tid & 63, g = l >> 4, c = l & 15;
    const int b = xb >> 2;
    const f32x4 z4 = {0.f, 0.f, 0.f, 0.f};

    // ---- hoisted invariants (small!) ----
    bf16x8 wf[2];                          // W1e frags, ht = 2w, 2w+1
    #pragma unroll
    for (int z = 0; z < 2; ++z)
        wf[z] = *(const bf16x8*)&W1ef[((2 * w + z) * 64 + l) * 8];

    bf16x8 pjb[4];                         // Pj octets: block-invariant (b fixed)
    #pragma unroll
    for (int pt = 0; pt < 4; ++pt)
        pjb[pt] = *(const bf16x8*)&Pjb[((long)(b * 64 + 16 * pt + c)) * 256
                                       + 32 * w + 8 * g];

    const float bias3 = b3[0];

    // stage mapping: tid<256 stages unit u=tid: (spt, sg, sc)
    const int spt = tid >> 6, sg = (tid >> 4) & 3, sc = tid & 15;
    const long erowbase = (long)xb * 1024 + 16 * spt + sc;

    f32x4 es0, es1;                        // in-flight staged edges
    if (tid < 256) {
        const float* ep = edges + erowbase * 32 + 8 * sg;
        es0 = *(const f32x4*)ep; es1 = *(const f32x4*)(ep + 4);
    }
    const float* PiB = Pi + ((long)xb * 16) * 256 + 32 * w + 8 * g;
    f32x4 pva0 = *(const f32x4*)PiB;       // Pi octet for batch 0
    f32x4 pva1 = *(const f32x4*)(PiB + 4);

    if (tid < 256) {                       // write batch-0 edges
        bf16x8 ev;
        #pragma unroll
        for (int j = 0; j < 4; ++j) { ev[j] = (bf16_t)es0[j]; ev[4 + j] = (bf16_t)es1[j]; }
        *(bf16x8*)&elds[0][tid * 8] = ev;
    }
    __syncthreads();

    f32x4 pvb0, pvb1;

    for (int t = 0; t < 16; ++t) {
        const int cur = t & 1;

        // issue next batch's loads early (hidden under L1+L2 of this batch)
        if (t < 15) {
            if (tid < 256) {
                const float* ep = edges + (erowbase + 64 * (t + 1)) * 32 + 8 * sg;
                es0 = *(const f32x4*)ep; es1 = *(const f32x4*)(ep + 4);
            }
            const float* pp = PiB + (t + 1) * 256;
            pvb0 = *(const f32x4*)pp; pvb1 = *(const f32x4*)(pp + 4);
        }

        // ---------------- layer 1 (sigma-fused, reg -> LDS octets) ----------
        {
            bf16x8 ebf[4];
            #pragma unroll
            for (int pt = 0; pt < 4; ++pt)
                ebf[pt] = *(const bf16x8*)&elds[cur][(pt * 64 + l) * 8];
            #pragma unroll
            for (int pt = 0; pt < 4; ++pt) {
                bf16x8 o;
                #pragma unroll
                for (int z = 0; z < 2; ++z) {
                    f32x4 a = mfma16(wf[z], ebf[pt], z4);
                    f32x4 pv = z ? pva1 : pva0;
                    #pragma unroll
                    for (int r = 0; r < 4; ++r) {
                        float v = a[r] + pv[r] + (float)pjb[pt][4 * z + r];
                        v = v > 0.f ? v : 0.f;
                        o[4 * z + r] = (bf16_t)v;
                    }
                }
                *(bf16x8*)&a1f[cur][((pt * 8 + w) * 64 + l) * 8] = o;
            }
        }

        // write-late: staged edges for batch t+1 into the other elds buffer
        if (t < 15 && tid < 256) {
            bf16x8 ev;
            #pragma unroll
            for (int j = 0; j < 4; ++j) { ev[j] = (bf16_t)es0[j]; ev[4 + j] = (bf16_t)es1[j]; }
            *(bf16x8*)&elds[cur ^ 1][tid * 8] = ev;
        }
        __syncthreads();                   // the one barrier per batch

        // deferred out-write for batch t-1 (all waves' part complete)
        if (t > 0 && tid < 64) {
            float s = bias3;
            #pragma unroll
            for (int ww = 0; ww < 8; ++ww) s += part[cur ^ 1][ww][tid];
            out[(long)xb * 1024 + (t - 1) * 64 + tid] = s;
        }

        // ---------------- layer 2 + layer 3 ----------------
        {
            f32x4 acc2[4][2];
            #pragma unroll
            for (int pt = 0; pt < 4; ++pt) { acc2[pt][0] = z4; acc2[pt][1] = z4; }
            #pragma unroll
            for (int ks = 0; ks < 8; ++ks) {
                bf16x8 af[4];
                #pragma unroll
                for (int pt = 0; pt < 4; ++pt)
                    af[pt] = *(const bf16x8*)&a1f[cur][((pt * 8 + ks) * 64 + l) * 8];
                #pragma unroll
                for (int cc = 0; cc < 2; ++cc) {
                    bf16x8 w2 = *(const bf16x8*)&W2f[((ks * 16 + 2 * w + cc) * 64 + l) * 8];
                    #pragma unroll
                    for (int pt = 0; pt < 4; ++pt)
                        acc2[pt][cc] = mfma16(w2, af[pt], acc2[pt][cc]);
                }
            }
            // L3: col = 32w + 16cc + 4g + r (in-lane), pair = 16pt + c
            f32x4 b2q[2], w3q[2];
            #pragma unroll
            for (int cc = 0; cc < 2; ++cc) {
                b2q[cc] = *(const f32x4*)&b2[32 * w + 16 * cc + 4 * g];
                w3q[cc] = *(const f32x4*)&W3[32 * w + 16 * cc + 4 * g];
            }
            #pragma unroll
            for (int pt = 0; pt < 4; ++pt) {
                float s = 0.f;
                #pragma unroll
                for (int cc = 0; cc < 2; ++cc)
                    #pragma unroll
                    for (int r = 0; r < 4; ++r) {
                        float v = acc2[pt][cc][r] + b2q[cc][r];
                        v = v > 0.f ? v : 0.f;
                        s = fmaf(v, w3q[cc][r], s);
                    }
                s += __shfl_xor(s, 16);    // sum the 4 g-groups
                s += __shfl_xor(s, 32);
                if (g == 0) part[cur][w][pt * 16 + c] = s;
            }
        }
        pva0 = pvb0; pva1 = pvb1;
    }

    __syncthreads();
    if (tid < 64) {                        // out for batch 15
        float s = bias3;
        #pragma unroll
        for (int ww = 0; ww < 8; ++ww) s += part[1][ww][tid];
        out[(long)xb * 1024 + 15 * 64 + tid] = s;
    }
}

extern "C" void kernel_launch(void* const* d_in, const int* in_sizes, int n_in,
                              void* d_out, int out_size, void* d_ws, size_t ws_size,
                              hipStream_t stream) {
    const float* nodes = (const float*)d_in[0];
    const float* edges = (const float*)d_in[1];
    const float* W1    = (const float*)d_in[2];
    const float* b1    = (const float*)d_in[3];
    const float* W2    = (const float*)d_in[4];
    const float* b2    = (const float*)d_in[5];
    const float* W3    = (const float*)d_in[6];
    const float* b3    = (const float*)d_in[7];
    float* out = (float*)d_out;

    char* ws = (char*)d_ws;
    float*  Pi   = (float*)ws;                                        // 8 MB
    bf16_t* Pjb  = (bf16_t*)(ws + (size_t)8 * 1024 * 1024);           // 4 MB
    bf16_t* W2f  = (bf16_t*)(ws + (size_t)12 * 1024 * 1024);          // 128 KB
    bf16_t* W1ef = (bf16_t*)(ws + (size_t)12 * 1024 * 1024 + 131072); // 16 KB

    prep_pack<<<dim3(36), dim3(256), 0, stream>>>(W1, W2, W1ef, W2f);
    prep_pij<<<dim3(512), dim3(256), 0, stream>>>(nodes, W1, b1, Pi, Pjb);
    mlp_main<<<dim3(512), dim3(512), 0, stream>>>(edges, Pi, Pjb, W1ef, W2f, b2, W3, b3, out);
}